// Round 14
// baseline (478.731 us; speedup 1.0000x reference)
//
#include <hip/hip_runtime.h>
#include <math.h>

#define KD 200
#define CD 352
#define NITER 32
#define LMB 0.01f

__device__ __forceinline__ float4 ld4(const float* p) { return *(const float4*)p; }
__device__ __forceinline__ void st4(float* p, float4 v) { *(float4*)p = v; }
__device__ __forceinline__ float rdlane(float v, int lane) {
    return __int_as_float(__builtin_amdgcn_readlane(__float_as_int(v), lane));
}

// ---------------- Kernel 1: G = A A^T, R = B A^T (batched, 64x64 tiles) ----------------
__global__ __launch_bounds__(256) void gemm_gr_kernel(
    const float* __restrict__ A, const float* __restrict__ B,
    float* __restrict__ G, float* __restrict__ R)
{
    __shared__ __align__(16) float Ms[16][72];   // [k][m]
    __shared__ __align__(16) float Ns[16][72];   // [k][n]
    const int tid = threadIdx.x;
    const int z = blockIdx.z;
    const int b = z >> 1, which = z & 1;
    const float* __restrict__ Xb = (which ? B : A) + (size_t)b * KD * CD;
    const float* __restrict__ Ab = A + (size_t)b * KD * CD;
    float* __restrict__ O = (which ? R : G) + (size_t)b * KD * KD;
    const int tileM = blockIdx.y * 64;
    const int tileN = blockIdx.x * 64;

    const int lm = tid >> 2;             // 0..63
    const int kq = (tid & 3) * 4;        // 0,4,8,12
    const int rowM = min(tileM + lm, KD - 1);
    const int rowN = min(tileN + lm, KD - 1);
    const float* __restrict__ Xrow = Xb + (size_t)rowM * CD;
    const float* __restrict__ Arow = Ab + (size_t)rowN * CD;

    const int ty = tid >> 4, tx = tid & 15;
    const int m0 = ty * 4, n0 = tx * 4;

    float acc[4][4] = {};
    for (int kk = 0; kk < CD; kk += 16) {
        const float4 vx = ld4(Xrow + kk + kq);
        const float4 va = ld4(Arow + kk + kq);
        __syncthreads();
        Ms[kq + 0][lm] = vx.x; Ms[kq + 1][lm] = vx.y;
        Ms[kq + 2][lm] = vx.z; Ms[kq + 3][lm] = vx.w;
        Ns[kq + 0][lm] = va.x; Ns[kq + 1][lm] = va.y;
        Ns[kq + 2][lm] = va.z; Ns[kq + 3][lm] = va.w;
        __syncthreads();
        #pragma unroll
        for (int k = 0; k < 16; ++k) {
            const float4 am = ld4(&Ms[k][m0]);
            const float4 an = ld4(&Ns[k][n0]);
            acc[0][0] = fmaf(am.x, an.x, acc[0][0]);
            acc[0][1] = fmaf(am.x, an.y, acc[0][1]);
            acc[0][2] = fmaf(am.x, an.z, acc[0][2]);
            acc[0][3] = fmaf(am.x, an.w, acc[0][3]);
            acc[1][0] = fmaf(am.y, an.x, acc[1][0]);
            acc[1][1] = fmaf(am.y, an.y, acc[1][1]);
            acc[1][2] = fmaf(am.y, an.z, acc[1][2]);
            acc[1][3] = fmaf(am.y, an.w, acc[1][3]);
            acc[2][0] = fmaf(am.z, an.x, acc[2][0]);
            acc[2][1] = fmaf(am.z, an.y, acc[2][1]);
            acc[2][2] = fmaf(am.z, an.z, acc[2][2]);
            acc[2][3] = fmaf(am.z, an.w, acc[2][3]);
            acc[3][0] = fmaf(am.w, an.x, acc[3][0]);
            acc[3][1] = fmaf(am.w, an.y, acc[3][1]);
            acc[3][2] = fmaf(am.w, an.z, acc[3][2]);
            acc[3][3] = fmaf(am.w, an.w, acc[3][3]);
        }
    }
    const int gn = tileN + n0;
    if (gn < KD) {
        #pragma unroll
        for (int i = 0; i < 4; ++i) {
            const int gm = tileM + m0 + i;
            if (gm < KD)
                st4(&O[(size_t)gm * KD + gn],
                    make_float4(acc[i][0], acc[i][1], acc[i][2], acc[i][3]));
        }
    }
}

// ------------- Kernel 2: batched standard PCG, 8 systems/block -------------
// Structure == R12 (proven 5.9 us/iter) with ONE change: each thread's G slice
// (4 rows {l,l+50,l+100,l+150} x its wave's 25 columns) is loaded ONCE into
// registers (gc[3][8] + g24, 100 VGPRs, constant-indexed after unroll) — the
// 32-iteration loop then has ZERO global loads. p broadcast via readlane from a
// branch-free LDS read (exec-mask/readlane hazard: lanes 50..63 must load too).
// State thread tid<400 = (row r=tid>>1, quad sq=tid&1) keeps x,r,p,lam,dinv,rz
// in registers. Direct dots (standard PCG; Gear recurrence diverged in fp32).
__global__ __launch_bounds__(512) void cg_kernel(
    const float* __restrict__ G, const float* __restrict__ R,
    const float* __restrict__ ex, const float* __restrict__ ey,
    float* __restrict__ out)
{
    __shared__ __align__(16) float P[KD * 8];          // p[c][s]
    __shared__ __align__(16) float PART[8 * KD * 8];   // [w][row][s], 51.2 KB
    __shared__ float WP1[8][8];
    __shared__ float WP2[8][8];
    __shared__ float red8[8];

    const int tid = threadIdx.x;
    const int w = tid >> 6, l = tid & 63;
    const int blk = blockIdx.x;
    const int b = blk / 25;
    const int i0 = (blk - b * 25) * 8;
    const int bK = b * KD;
    const float* __restrict__ Gb = G + (size_t)b * KD * KD;

    // ---- scale = max(ex[b,:], ey[b,:]) ----
    float mxv = 0.f;
    if (tid < KD) mxv = fmaxf(ex[bK + tid], ey[bK + tid]);
    #pragma unroll
    for (int off = 32; off > 0; off >>= 1)
        mxv = fmaxf(mxv, __shfl_down(mxv, off, 64));
    if (l == 0) red8[w] = mxv;
    __syncthreads();
    float scale = red8[0];
    #pragma unroll
    for (int wv = 1; wv < 8; ++wv) scale = fmaxf(scale, red8[wv]);
    const float inv_scale = 1.0f / scale;

    // ---- G register cache (iteration-invariant) ----
    const bool mact = (l < 50);
    const int gcol = mact ? l : 49;        // lanes 50..63 duplicate row-group 49 (discarded)
    float4 gc[3][8];
    #pragma unroll
    for (int t = 0; t < 3; ++t) {
        const int jc = w + t * 8;
        const float* __restrict__ gp = Gb + (size_t)(jc * 8) * KD + gcol;
        #pragma unroll
        for (int dc = 0; dc < 8; ++dc) {
            gc[t][dc] = make_float4(gp[0], gp[50], gp[100], gp[150]);
            gp += KD;
        }
    }
    float4 g24;
    {
        const float* __restrict__ gp = Gb + (size_t)(192 + w) * KD + gcol;
        g24 = make_float4(gp[0], gp[50], gp[100], gp[150]);
    }

    // ---- state init (registers) ----
    const bool stid = tid < 400;
    const int r = tid >> 1, sq = tid & 1;
    float lam[4], dinv[4], rr[4], xx[4], pp[4], rz4[4];
    if (stid) {
        const float exj = ex[bK + r] * inv_scale;
        const float e1 = sqrtf(exj);
        const float gdiag = Gb[(size_t)r * KD + r];
        const float* __restrict__ Rb = R + (size_t)(bK + i0 + sq * 4) * KD + r;
        #pragma unroll
        for (int j = 0; j < 4; ++j) {
            const float eyi = ey[bK + i0 + sq * 4 + j] * inv_scale;
            const float e2 = sqrtf(eyi);
            const float dn = exj + eyi;
            const float re = e2 - e1;
            lam[j] = LMB * ((re * re + 1.f) / (dn * dn));
            dinv[j] = 1.f / (gdiag + lam[j]);
            rr[j] = Rb[(size_t)j * KD];
            pp[j] = rr[j] * dinv[j];      // p0 = z0
            xx[j] = 0.f;
        }
        st4(&P[r * 8 + sq * 4], make_float4(pp[0], pp[1], pp[2], pp[3]));
    }
    // rz0 partials
    {
        float vg[4];
        #pragma unroll
        for (int j = 0; j < 4; ++j) vg[j] = stid ? rr[j] * pp[j] : 0.f;
        #pragma unroll
        for (int off = 2; off < 64; off <<= 1)
            #pragma unroll
            for (int j = 0; j < 4; ++j) vg[j] += __shfl_xor(vg[j], off, 64);
        if (l < 2) {
            #pragma unroll
            for (int j = 0; j < 4; ++j) WP1[w][l * 4 + j] = vg[j];
        }
    }
    __syncthreads();
    if (stid) {
        #pragma unroll
        for (int j = 0; j < 4; ++j) {
            float s = 0.f;
            #pragma unroll
            for (int w8 = 0; w8 < 8; ++w8) s += WP1[w8][sq * 4 + j];
            rz4[j] = s;
        }
    }

    // ================= standard PCG main loop =================
    for (int k = 0; k < NITER; ++k) {
        __syncthreads();                   // B1: P stable, WP consumed

        // ---- matvec partials from register-cached G ----
        float acc[4][8];
        #pragma unroll
        for (int j = 0; j < 4; ++j)
            #pragma unroll
            for (int s = 0; s < 8; ++s) acc[j][s] = 0.f;

        #pragma unroll
        for (int t = 0; t < 3; ++t) {
            const int jc = w + t * 8;
            const float pv = P[jc * 64 + l];   // ALL lanes load (readlane source)
            #pragma unroll
            for (int dc = 0; dc < 8; ++dc) {
                const float4 g = gc[t][dc];
                #pragma unroll
                for (int s = 0; s < 8; ++s) {
                    const float ps = rdlane(pv, dc * 8 + s);
                    acc[0][s] = fmaf(g.x, ps, acc[0][s]);
                    acc[1][s] = fmaf(g.y, ps, acc[1][s]);
                    acc[2][s] = fmaf(g.z, ps, acc[2][s]);
                    acc[3][s] = fmaf(g.w, ps, acc[3][s]);
                }
            }
        }
        {   // chunk 24 (c = 192..199): one column per wave
            const float pv24 = P[24 * 64 + l];
            #pragma unroll
            for (int s = 0; s < 8; ++s) {
                const float ps = rdlane(pv24, w * 8 + s);
                acc[0][s] = fmaf(g24.x, ps, acc[0][s]);
                acc[1][s] = fmaf(g24.y, ps, acc[1][s]);
                acc[2][s] = fmaf(g24.z, ps, acc[2][s]);
                acc[3][s] = fmaf(g24.w, ps, acc[3][s]);
            }
        }
        if (mact) {
            #pragma unroll
            for (int j = 0; j < 4; ++j) {
                float* pw = &PART[w * (KD * 8) + (50 * j + l) * 8];
                st4(pw,     make_float4(acc[j][0], acc[j][1], acc[j][2], acc[j][3]));
                st4(pw + 4, make_float4(acc[j][4], acc[j][5], acc[j][6], acc[j][7]));
            }
        }
        __syncthreads();                   // B2: PART ready

        // ---- q = A p (combine) + pq partials ----
        float qq[4], vq[4];
        if (stid) {
            float4 sum = make_float4(0.f, 0.f, 0.f, 0.f);
            #pragma unroll
            for (int w8 = 0; w8 < 8; ++w8) {
                const float4 f = ld4(&PART[w8 * (KD * 8) + r * 8 + sq * 4]);
                sum.x += f.x; sum.y += f.y; sum.z += f.z; sum.w += f.w;
            }
            qq[0] = fmaf(lam[0], pp[0], sum.x);
            qq[1] = fmaf(lam[1], pp[1], sum.y);
            qq[2] = fmaf(lam[2], pp[2], sum.z);
            qq[3] = fmaf(lam[3], pp[3], sum.w);
            #pragma unroll
            for (int j = 0; j < 4; ++j) vq[j] = pp[j] * qq[j];
        } else {
            #pragma unroll
            for (int j = 0; j < 4; ++j) { qq[j] = 0.f; vq[j] = 0.f; }
        }
        #pragma unroll
        for (int off = 2; off < 64; off <<= 1)
            #pragma unroll
            for (int j = 0; j < 4; ++j) vq[j] += __shfl_xor(vq[j], off, 64);
        if (l < 2) {
            #pragma unroll
            for (int j = 0; j < 4; ++j) WP1[w][l * 4 + j] = vq[j];
        }
        __syncthreads();                   // B3: pq ready

        // ---- alpha, x/r update, rz partials ----
        float vr[4];
        if (stid) {
            #pragma unroll
            for (int j = 0; j < 4; ++j) {
                float pq = 0.f;
                #pragma unroll
                for (int w8 = 0; w8 < 8; ++w8) pq += WP1[w8][sq * 4 + j];
                const float alpha = rz4[j] / pq;
                xx[j] = fmaf(alpha, pp[j], xx[j]);
                rr[j] = fmaf(-alpha, qq[j], rr[j]);
                vr[j] = rr[j] * rr[j] * dinv[j];
            }
        } else {
            #pragma unroll
            for (int j = 0; j < 4; ++j) vr[j] = 0.f;
        }
        #pragma unroll
        for (int off = 2; off < 64; off <<= 1)
            #pragma unroll
            for (int j = 0; j < 4; ++j) vr[j] += __shfl_xor(vr[j], off, 64);
        if (l < 2) {
            #pragma unroll
            for (int j = 0; j < 4; ++j) WP2[w][l * 4 + j] = vr[j];
        }
        __syncthreads();                   // B4: rz ready

        // ---- beta, p update ----
        if (stid) {
            #pragma unroll
            for (int j = 0; j < 4; ++j) {
                float rzn = 0.f;
                #pragma unroll
                for (int w8 = 0; w8 < 8; ++w8) rzn += WP2[w8][sq * 4 + j];
                const float beta = rzn / rz4[j];
                rz4[j] = rzn;
                pp[j] = fmaf(beta, pp[j], rr[j] * dinv[j]);   // p = z + beta p
            }
            st4(&P[r * 8 + sq * 4], make_float4(pp[0], pp[1], pp[2], pp[3]));
        }
    }

    // ---- store x ----
    if (stid) {
        float* __restrict__ Ob = out + (size_t)(bK + i0 + sq * 4) * KD + r;
        #pragma unroll
        for (int j = 0; j < 4; ++j)
            Ob[(size_t)j * KD] = xx[j];
    }
}

extern "C" void kernel_launch(void* const* d_in, const int* in_sizes, int n_in,
                              void* d_out, int out_size, void* d_ws, size_t ws_size,
                              hipStream_t stream) {
    const float* A  = (const float*)d_in[0];
    const float* B  = (const float*)d_in[1];
    const float* ex = (const float*)d_in[2];
    const float* ey = (const float*)d_in[3];
    float* out = (float*)d_out;

    float* G = (float*)d_ws;
    float* R = G + 8 * KD * KD;

    dim3 grid1(4, 4, 16);
    gemm_gr_kernel<<<grid1, 256, 0, stream>>>(A, B, G, R);

    cg_kernel<<<200, 512, 0, stream>>>(G, R, ex, ey, out);
}

// Round 15
// 239.850 us; speedup vs baseline: 1.9960x; 1.9960x over previous
//
#include <hip/hip_runtime.h>
#include <math.h>

#define KD 200
#define CD 352
#define NITER 28
#define LMB 0.01f

__device__ __forceinline__ float4 ld4(const float* p) { return *(const float4*)p; }
__device__ __forceinline__ void st4(float* p, float4 v) { *(float4*)p = v; }
__device__ __forceinline__ float rdlane(float v, int lane) {
    return __int_as_float(__builtin_amdgcn_readlane(__float_as_int(v), lane));
}

// ---------------- Kernel 1: G = A A^T, R = B A^T (batched, 64x64 tiles) ----------------
__global__ __launch_bounds__(256) void gemm_gr_kernel(
    const float* __restrict__ A, const float* __restrict__ B,
    float* __restrict__ G, float* __restrict__ R)
{
    __shared__ __align__(16) float Ms[16][72];   // [k][m]
    __shared__ __align__(16) float Ns[16][72];   // [k][n]
    const int tid = threadIdx.x;
    const int z = blockIdx.z;
    const int b = z >> 1, which = z & 1;
    const float* __restrict__ Xb = (which ? B : A) + (size_t)b * KD * CD;
    const float* __restrict__ Ab = A + (size_t)b * KD * CD;
    float* __restrict__ O = (which ? R : G) + (size_t)b * KD * KD;
    const int tileM = blockIdx.y * 64;
    const int tileN = blockIdx.x * 64;

    const int lm = tid >> 2;             // 0..63
    const int kq = (tid & 3) * 4;        // 0,4,8,12
    const int rowM = min(tileM + lm, KD - 1);
    const int rowN = min(tileN + lm, KD - 1);
    const float* __restrict__ Xrow = Xb + (size_t)rowM * CD;
    const float* __restrict__ Arow = Ab + (size_t)rowN * CD;

    const int ty = tid >> 4, tx = tid & 15;
    const int m0 = ty * 4, n0 = tx * 4;

    float acc[4][4] = {};
    for (int kk = 0; kk < CD; kk += 16) {
        const float4 vx = ld4(Xrow + kk + kq);
        const float4 va = ld4(Arow + kk + kq);
        __syncthreads();
        Ms[kq + 0][lm] = vx.x; Ms[kq + 1][lm] = vx.y;
        Ms[kq + 2][lm] = vx.z; Ms[kq + 3][lm] = vx.w;
        Ns[kq + 0][lm] = va.x; Ns[kq + 1][lm] = va.y;
        Ns[kq + 2][lm] = va.z; Ns[kq + 3][lm] = va.w;
        __syncthreads();
        #pragma unroll
        for (int k = 0; k < 16; ++k) {
            const float4 am = ld4(&Ms[k][m0]);
            const float4 an = ld4(&Ns[k][n0]);
            acc[0][0] = fmaf(am.x, an.x, acc[0][0]);
            acc[0][1] = fmaf(am.x, an.y, acc[0][1]);
            acc[0][2] = fmaf(am.x, an.z, acc[0][2]);
            acc[0][3] = fmaf(am.x, an.w, acc[0][3]);
            acc[1][0] = fmaf(am.y, an.x, acc[1][0]);
            acc[1][1] = fmaf(am.y, an.y, acc[1][1]);
            acc[1][2] = fmaf(am.y, an.z, acc[1][2]);
            acc[1][3] = fmaf(am.y, an.w, acc[1][3]);
            acc[2][0] = fmaf(am.z, an.x, acc[2][0]);
            acc[2][1] = fmaf(am.z, an.y, acc[2][1]);
            acc[2][2] = fmaf(am.z, an.z, acc[2][2]);
            acc[2][3] = fmaf(am.z, an.w, acc[2][3]);
            acc[3][0] = fmaf(am.w, an.x, acc[3][0]);
            acc[3][1] = fmaf(am.w, an.y, acc[3][1]);
            acc[3][2] = fmaf(am.w, an.z, acc[3][2]);
            acc[3][3] = fmaf(am.w, an.w, acc[3][3]);
        }
    }
    const int gn = tileN + n0;
    if (gn < KD) {
        #pragma unroll
        for (int i = 0; i < 4; ++i) {
            const int gm = tileM + m0 + i;
            if (gm < KD)
                st4(&O[(size_t)gm * KD + gn],
                    make_float4(acc[i][0], acc[i][1], acc[i][2], acc[i][3]));
        }
    }
}

// ------------- Kernel 2: batched standard PCG, 8 systems/block (R12 structure) -------------
// Matvec: lane l (l<50) of wave w owns rows {l,l+50,l+100,l+150}; wave w covers
// column-chunks {w, w+8, w+16} + one column of chunk 24. Chunk t=0's G values are
// cached in registers ONCE (g0[8] = 32 VGPRs; total ~104 < the 128-VGPR compiler cap
// — R14 showed exceeding it spills the cache to scratch: 800 MB FETCH). p broadcast
// via readlane from a branch-free LDS read (exec-mask/readlane hazard: lanes 50..63
// must load too). State thread tid<400 keeps x,r,p,lam,dinv,rz in registers.
// Direct dots (standard PCG; Gear recurrence diverged in fp32).
__global__ __launch_bounds__(512) void cg_kernel(
    const float* __restrict__ G, const float* __restrict__ R,
    const float* __restrict__ ex, const float* __restrict__ ey,
    float* __restrict__ out)
{
    __shared__ __align__(16) float P[KD * 8];          // p[c][s]
    __shared__ __align__(16) float PART[8 * KD * 8];   // [w][row][s], 51.2 KB
    __shared__ float WP1[8][8];
    __shared__ float WP2[8][8];
    __shared__ float red8[8];

    const int tid = threadIdx.x;
    const int w = tid >> 6, l = tid & 63;
    const int blk = blockIdx.x;
    const int b = blk / 25;
    const int i0 = (blk - b * 25) * 8;
    const int bK = b * KD;
    const float* __restrict__ Gb = G + (size_t)b * KD * KD;

    // ---- scale = max(ex[b,:], ey[b,:]) ----
    float mxv = 0.f;
    if (tid < KD) mxv = fmaxf(ex[bK + tid], ey[bK + tid]);
    #pragma unroll
    for (int off = 32; off > 0; off >>= 1)
        mxv = fmaxf(mxv, __shfl_down(mxv, off, 64));
    if (l == 0) red8[w] = mxv;
    __syncthreads();
    float scale = red8[0];
    #pragma unroll
    for (int wv = 1; wv < 8; ++wv) scale = fmaxf(scale, red8[wv]);
    const float inv_scale = 1.0f / scale;

    const bool mact = (l < 50);
    const int gcol = mact ? l : 49;        // lanes 50..63 duplicate row-group 49 (discarded)

    // ---- register cache for chunk t=0 only (32 VGPRs; fits under the cap) ----
    float4 g0[8];
    {
        const float* __restrict__ gp = Gb + (size_t)(w * 8) * KD + gcol;
        #pragma unroll
        for (int dc = 0; dc < 8; ++dc) {
            g0[dc] = make_float4(gp[0], gp[50], gp[100], gp[150]);
            gp += KD;
        }
    }

    // ---- state init (registers) ----
    const bool stid = tid < 400;
    const int r = tid >> 1, sq = tid & 1;
    float lam[4], dinv[4], rr[4], xx[4], pp[4], rz4[4];
    if (stid) {
        const float exj = ex[bK + r] * inv_scale;
        const float e1 = sqrtf(exj);
        const float gdiag = Gb[(size_t)r * KD + r];
        const float* __restrict__ Rb = R + (size_t)(bK + i0 + sq * 4) * KD + r;
        #pragma unroll
        for (int j = 0; j < 4; ++j) {
            const float eyi = ey[bK + i0 + sq * 4 + j] * inv_scale;
            const float e2 = sqrtf(eyi);
            const float dn = exj + eyi;
            const float re = e2 - e1;
            lam[j] = LMB * ((re * re + 1.f) / (dn * dn));
            dinv[j] = 1.f / (gdiag + lam[j]);
            rr[j] = Rb[(size_t)j * KD];
            pp[j] = rr[j] * dinv[j];      // p0 = z0
            xx[j] = 0.f;
        }
        st4(&P[r * 8 + sq * 4], make_float4(pp[0], pp[1], pp[2], pp[3]));
    }
    // rz0 partials
    {
        float vg[4];
        #pragma unroll
        for (int j = 0; j < 4; ++j) vg[j] = stid ? rr[j] * pp[j] : 0.f;
        #pragma unroll
        for (int off = 2; off < 64; off <<= 1)
            #pragma unroll
            for (int j = 0; j < 4; ++j) vg[j] += __shfl_xor(vg[j], off, 64);
        if (l < 2) {
            #pragma unroll
            for (int j = 0; j < 4; ++j) WP1[w][l * 4 + j] = vg[j];
        }
    }
    __syncthreads();
    if (stid) {
        #pragma unroll
        for (int j = 0; j < 4; ++j) {
            float s = 0.f;
            #pragma unroll
            for (int w8 = 0; w8 < 8; ++w8) s += WP1[w8][sq * 4 + j];
            rz4[j] = s;
        }
    }

    // ================= standard PCG main loop =================
    for (int k = 0; k < NITER; ++k) {
        __syncthreads();                   // B1: P stable, WP consumed

        float acc[4][8];
        #pragma unroll
        for (int j = 0; j < 4; ++j)
            #pragma unroll
            for (int s = 0; s < 8; ++s) acc[j][s] = 0.f;

        // chunk t=0 from the register cache
        {
            const float pv = P[w * 64 + l];    // ALL lanes load (readlane source)
            #pragma unroll
            for (int dc = 0; dc < 8; ++dc) {
                const float4 g = g0[dc];
                #pragma unroll
                for (int s = 0; s < 8; ++s) {
                    const float ps = rdlane(pv, dc * 8 + s);
                    acc[0][s] = fmaf(g.x, ps, acc[0][s]);
                    acc[1][s] = fmaf(g.y, ps, acc[1][s]);
                    acc[2][s] = fmaf(g.z, ps, acc[2][s]);
                    acc[3][s] = fmaf(g.w, ps, acc[3][s]);
                }
            }
        }
        // chunks t=1,2 streamed from L2 (R12 pattern)
        #pragma unroll
        for (int t = 1; t < 3; ++t) {
            const int jc = w + t * 8;
            const float pv = P[jc * 64 + l];
            const float* __restrict__ gp = Gb + (size_t)(jc * 8) * KD + gcol;
            #pragma unroll
            for (int dc = 0; dc < 8; ++dc) {
                const float g0v = gp[0];
                const float g1v = gp[50];
                const float g2v = gp[100];
                const float g3v = gp[150];
                #pragma unroll
                for (int s = 0; s < 8; ++s) {
                    const float ps = rdlane(pv, dc * 8 + s);
                    acc[0][s] = fmaf(g0v, ps, acc[0][s]);
                    acc[1][s] = fmaf(g1v, ps, acc[1][s]);
                    acc[2][s] = fmaf(g2v, ps, acc[2][s]);
                    acc[3][s] = fmaf(g3v, ps, acc[3][s]);
                }
                gp += KD;
            }
        }
        {   // chunk 24 (c = 192..199): one column per wave
            const float pv24 = P[24 * 64 + l];
            const float* __restrict__ gp24 = Gb + (size_t)(192 + w) * KD + gcol;
            const float g0v = gp24[0];
            const float g1v = gp24[50];
            const float g2v = gp24[100];
            const float g3v = gp24[150];
            #pragma unroll
            for (int s = 0; s < 8; ++s) {
                const float ps = rdlane(pv24, w * 8 + s);
                acc[0][s] = fmaf(g0v, ps, acc[0][s]);
                acc[1][s] = fmaf(g1v, ps, acc[1][s]);
                acc[2][s] = fmaf(g2v, ps, acc[2][s]);
                acc[3][s] = fmaf(g3v, ps, acc[3][s]);
            }
        }
        if (mact) {
            #pragma unroll
            for (int j = 0; j < 4; ++j) {
                float* pw = &PART[w * (KD * 8) + (50 * j + l) * 8];
                st4(pw,     make_float4(acc[j][0], acc[j][1], acc[j][2], acc[j][3]));
                st4(pw + 4, make_float4(acc[j][4], acc[j][5], acc[j][6], acc[j][7]));
            }
        }
        __syncthreads();                   // B2: PART ready

        // ---- q = A p (combine) + pq partials ----
        float qq[4], vq[4];
        if (stid) {
            float4 sum = make_float4(0.f, 0.f, 0.f, 0.f);
            #pragma unroll
            for (int w8 = 0; w8 < 8; ++w8) {
                const float4 f = ld4(&PART[w8 * (KD * 8) + r * 8 + sq * 4]);
                sum.x += f.x; sum.y += f.y; sum.z += f.z; sum.w += f.w;
            }
            qq[0] = fmaf(lam[0], pp[0], sum.x);
            qq[1] = fmaf(lam[1], pp[1], sum.y);
            qq[2] = fmaf(lam[2], pp[2], sum.z);
            qq[3] = fmaf(lam[3], pp[3], sum.w);
            #pragma unroll
            for (int j = 0; j < 4; ++j) vq[j] = pp[j] * qq[j];
        } else {
            #pragma unroll
            for (int j = 0; j < 4; ++j) { qq[j] = 0.f; vq[j] = 0.f; }
        }
        #pragma unroll
        for (int off = 2; off < 64; off <<= 1)
            #pragma unroll
            for (int j = 0; j < 4; ++j) vq[j] += __shfl_xor(vq[j], off, 64);
        if (l < 2) {
            #pragma unroll
            for (int j = 0; j < 4; ++j) WP1[w][l * 4 + j] = vq[j];
        }
        __syncthreads();                   // B3: pq ready

        // ---- alpha, x/r update, rz partials ----
        float vr[4];
        if (stid) {
            #pragma unroll
            for (int j = 0; j < 4; ++j) {
                float pq = 0.f;
                #pragma unroll
                for (int w8 = 0; w8 < 8; ++w8) pq += WP1[w8][sq * 4 + j];
                const float alpha = rz4[j] / pq;
                xx[j] = fmaf(alpha, pp[j], xx[j]);
                rr[j] = fmaf(-alpha, qq[j], rr[j]);
                vr[j] = rr[j] * rr[j] * dinv[j];
            }
        } else {
            #pragma unroll
            for (int j = 0; j < 4; ++j) vr[j] = 0.f;
        }
        #pragma unroll
        for (int off = 2; off < 64; off <<= 1)
            #pragma unroll
            for (int j = 0; j < 4; ++j) vr[j] += __shfl_xor(vr[j], off, 64);
        if (l < 2) {
            #pragma unroll
            for (int j = 0; j < 4; ++j) WP2[w][l * 4 + j] = vr[j];
        }
        __syncthreads();                   // B4: rz ready

        // ---- beta, p update ----
        if (stid) {
            #pragma unroll
            for (int j = 0; j < 4; ++j) {
                float rzn = 0.f;
                #pragma unroll
                for (int w8 = 0; w8 < 8; ++w8) rzn += WP2[w8][sq * 4 + j];
                const float beta = rzn / rz4[j];
                rz4[j] = rzn;
                pp[j] = fmaf(beta, pp[j], rr[j] * dinv[j]);   // p = z + beta p
            }
            st4(&P[r * 8 + sq * 4], make_float4(pp[0], pp[1], pp[2], pp[3]));
        }
    }

    // ---- store x ----
    if (stid) {
        float* __restrict__ Ob = out + (size_t)(bK + i0 + sq * 4) * KD + r;
        #pragma unroll
        for (int j = 0; j < 4; ++j)
            Ob[(size_t)j * KD] = xx[j];
    }
}

extern "C" void kernel_launch(void* const* d_in, const int* in_sizes, int n_in,
                              void* d_out, int out_size, void* d_ws, size_t ws_size,
                              hipStream_t stream) {
    const float* A  = (const float*)d_in[0];
    const float* B  = (const float*)d_in[1];
    const float* ex = (const float*)d_in[2];
    const float* ey = (const float*)d_in[3];
    float* out = (float*)d_out;

    float* G = (float*)d_ws;
    float* R = G + 8 * KD * KD;

    dim3 grid1(4, 4, 16);
    gemm_gr_kernel<<<grid1, 256, 0, stream>>>(A, B, G, R);

    cg_kernel<<<200, 512, 0, stream>>>(G, R, ex, ey, out);
}